// Round 1
// baseline (435.576 us; speedup 1.0000x reference)
//
#include <hip/hip_runtime.h>
#include <math.h>

#define NN 20000
#define EE 320000
#define DD 256
#define ETOT (EE + NN)

__device__ __forceinline__ float gelu_exact(float x) {
    return 0.5f * x * (1.0f + erff(x * 0.70710678118654752f));
}

// ---------------- row-normalize: one wave per row ----------------
__global__ __launch_bounds__(256) void norm_k(const float* __restrict__ X, float* __restrict__ Y) {
    int wave = (blockIdx.x * 256 + threadIdx.x) >> 6;
    int lane = threadIdx.x & 63;
    const float4 v = *(const float4*)&X[wave * DD + lane * 4];
    float ss = v.x * v.x + v.y * v.y + v.z * v.z + v.w * v.w;
    for (int off = 32; off > 0; off >>= 1) ss += __shfl_down(ss, off, 64);
    ss = __shfl(ss, 0, 64);
    float n = sqrtf(ss);
    if (n == 0.0f) n = 1e-8f;
    float inv = 1.0f / n;
    float4 o; o.x = v.x * inv; o.y = v.y * inv; o.z = v.z * inv; o.w = v.w * inv;
    *(float4*)&Y[wave * DD + lane * 4] = o;
}

// ---------------- CSR build ----------------
__global__ void initdeg_k(int* deg) {
    int i = blockIdx.x * 256 + threadIdx.x;
    if (i < NN) deg[i] = 1;  // self loop
}

__global__ void count_k(const int* __restrict__ ei, int* deg) {
    int e = blockIdx.x * 256 + threadIdx.x;
    if (e < EE) atomicAdd(&deg[ei[EE + e]], 1);
}

#define SCAN_T 1024
#define ITEMS 20
__global__ __launch_bounds__(SCAN_T) void scan_k(const int* __restrict__ deg, int* __restrict__ offs,
                                                 int* __restrict__ cursor) {
    __shared__ int part[SCAN_T];
    int t = threadIdx.x;
    int base = t * ITEMS;
    int local[ITEMS];
    int sum = 0;
#pragma unroll
    for (int i = 0; i < ITEMS; ++i) {
        int idx = base + i;
        int v = (idx < NN) ? deg[idx] : 0;
        local[i] = v;
        sum += v;
    }
    part[t] = sum;
    __syncthreads();
    for (int s = 1; s < SCAN_T; s <<= 1) {
        int v = (t >= s) ? part[t - s] : 0;
        __syncthreads();
        part[t] += v;
        __syncthreads();
    }
    int run = (t == 0) ? 0 : part[t - 1];
#pragma unroll
    for (int i = 0; i < ITEMS; ++i) {
        int idx = base + i;
        if (idx < NN) {
            offs[idx] = run;
            cursor[idx] = run;
            run += local[i];
        }
    }
    if (t == SCAN_T - 1) offs[NN] = part[SCAN_T - 1];
}

__global__ void fill_k(const int* __restrict__ ei, int* cursor, int* __restrict__ csr) {
    int e = blockIdx.x * 256 + threadIdx.x;
    if (e < EE) {
        int s = ei[e];
        int d = ei[EE + e];
        int p = atomicAdd(&cursor[d], 1);
        csr[p] = s;
    } else if (e < EE + NN) {
        int i = e - EE;
        int p = atomicAdd(&cursor[i], 1);
        csr[p] = i;
    }
}

// ---------------- fp32 GEMM: H[N,256] = X[N,256] @ W[256,256] ----------------
// 64x64 tile per 256-thread block, 4x4 per thread, K-chunks of 16.
__global__ __launch_bounds__(256) void gemm_k(const float* __restrict__ X, const float* __restrict__ W,
                                              float* __restrict__ H) {
    __shared__ float As[16][68];  // As[k][m]
    __shared__ float Ws[16][68];  // Ws[k][n]
    int t = threadIdx.x;
    int m0 = blockIdx.x * 64;
    int n0 = blockIdx.y * 64;
    int tx = t & 15, ty = t >> 4;

    float acc[4][4] = {{0.0f}};

    int lr = t >> 2;             // 0..63: row within A tile
    int lk = (t & 3) << 2;       // 0,4,8,12: k offset
    int wk = t >> 4;             // 0..15: k row for W load
    int wn = (t & 15) << 2;      // col offset for W load
    int arow = m0 + lr;
    bool avalid = arow < NN;

    for (int k0 = 0; k0 < DD; k0 += 16) {
        float4 av = avalid ? *(const float4*)&X[arow * DD + k0 + lk] : make_float4(0, 0, 0, 0);
        As[lk + 0][lr] = av.x;
        As[lk + 1][lr] = av.y;
        As[lk + 2][lr] = av.z;
        As[lk + 3][lr] = av.w;
        *(float4*)&Ws[wk][wn] = *(const float4*)&W[(k0 + wk) * DD + n0 + wn];
        __syncthreads();
#pragma unroll
        for (int k = 0; k < 16; ++k) {
            float4 a = *(const float4*)&As[k][ty << 2];
            float4 b = *(const float4*)&Ws[k][tx << 2];
            acc[0][0] += a.x * b.x; acc[0][1] += a.x * b.y; acc[0][2] += a.x * b.z; acc[0][3] += a.x * b.w;
            acc[1][0] += a.y * b.x; acc[1][1] += a.y * b.y; acc[1][2] += a.y * b.z; acc[1][3] += a.y * b.w;
            acc[2][0] += a.z * b.x; acc[2][1] += a.z * b.y; acc[2][2] += a.z * b.z; acc[2][3] += a.z * b.w;
            acc[3][0] += a.w * b.x; acc[3][1] += a.w * b.y; acc[3][2] += a.w * b.z; acc[3][3] += a.w * b.w;
        }
        __syncthreads();
    }
#pragma unroll
    for (int i = 0; i < 4; ++i) {
        int row = m0 + (ty << 2) + i;
        if (row < NN) {
            float4 o = make_float4(acc[i][0], acc[i][1], acc[i][2], acc[i][3]);
            *(float4*)&H[row * DD + n0 + (tx << 2)] = o;
        }
    }
}

// ---------------- s,d per node: one wave per row ----------------
__global__ __launch_bounds__(256) void sd_k(const float* __restrict__ H, const float* __restrict__ a_s,
                                            const float* __restrict__ a_d, float* __restrict__ sArr,
                                            float* __restrict__ dArr) {
    int wave = (blockIdx.x * 256 + threadIdx.x) >> 6;
    int lane = threadIdx.x & 63;
    const float4 h = *(const float4*)&H[wave * DD + lane * 4];
    const float4 vs = *(const float4*)&a_s[lane * 4];
    const float4 vd = *(const float4*)&a_d[lane * 4];
    float s = h.x * vs.x + h.y * vs.y + h.z * vs.z + h.w * vs.w;
    float d = h.x * vd.x + h.y * vd.y + h.z * vd.z + h.w * vd.w;
    for (int off = 32; off > 0; off >>= 1) {
        s += __shfl_down(s, off, 64);
        d += __shfl_down(d, off, 64);
    }
    if (lane == 0) {
        sArr[wave] = s;
        dArr[wave] = d;
    }
}

// ---------------- segment-softmax aggregation + bias + gelu: one wave per dst ----------------
__global__ __launch_bounds__(256) void agg_k(const float* __restrict__ H, const float* __restrict__ sArr,
                                             const float* __restrict__ dArr, const int* __restrict__ offs,
                                             const int* __restrict__ csr, const float* __restrict__ bias,
                                             float* __restrict__ out) {
    int dst = (blockIdx.x * 256 + threadIdx.x) >> 6;
    int lane = threadIdx.x & 63;
    int beg = offs[dst], end = offs[dst + 1];
    float dd = dArr[dst];
    float4 acc = make_float4(0, 0, 0, 0);
    float den = 0.0f;
    for (int base = beg; base < end; base += 64) {
        int cnt = end - base;
        if (cnt > 64) cnt = 64;
        int srcl = 0;
        float wl = 0.0f;
        if (lane < cnt) {
            srcl = csr[base + lane];
            float a = sArr[srcl] + dd;
            a = (a > 0.0f) ? a : 0.2f * a;
            wl = expf(a);
        }
        for (int j = 0; j < cnt; ++j) {
            int src = __shfl(srcl, j, 64);
            float w = __shfl(wl, j, 64);
            const float4 hv = *(const float4*)&H[src * DD + lane * 4];
            acc.x += w * hv.x;
            acc.y += w * hv.y;
            acc.z += w * hv.z;
            acc.w += w * hv.w;
            den += w;
        }
    }
    float inv = 1.0f / den;
    const float4 b = *(const float4*)&bias[lane * 4];
    float4 o;
    o.x = gelu_exact(acc.x * inv + b.x);
    o.y = gelu_exact(acc.y * inv + b.y);
    o.z = gelu_exact(acc.z * inv + b.z);
    o.w = gelu_exact(acc.w * inv + b.w);
    *(float4*)&out[dst * DD + lane * 4] = o;
}

extern "C" void kernel_launch(void* const* d_in, const int* in_sizes, int n_in,
                              void* d_out, int out_size, void* d_ws, size_t ws_size,
                              hipStream_t stream) {
    const float* x  = (const float*)d_in[0];
    const int* ei   = (const int*)d_in[1];
    // d_in[2]=edge_attr (ignored), d_in[3]=batch (ignored)
    const float* W1 = (const float*)d_in[4];
    const float* as1 = (const float*)d_in[5];
    const float* ad1 = (const float*)d_in[6];
    const float* b1 = (const float*)d_in[7];
    const float* W2 = (const float*)d_in[8];
    const float* as2 = (const float*)d_in[9];
    const float* ad2 = (const float*)d_in[10];
    const float* b2 = (const float*)d_in[11];
    const float* W3 = (const float*)d_in[12];
    const float* as3 = (const float*)d_in[13];
    const float* ad3 = (const float*)d_in[14];
    const float* b3 = (const float*)d_in[15];

    float* A = (float*)d_ws;               // ping buffer [N,256]
    float* B = A + (size_t)NN * DD;        // h buffer    [N,256]
    float* sArr = B + (size_t)NN * DD;     // [N]
    float* dArr = sArr + NN;               // [N]
    int* offs = (int*)(dArr + NN);         // [N+1]
    int* cursor = offs + (NN + 1);         // [N]
    int* csr = cursor + NN;                // [ETOT]
    int* deg = csr + ETOT;                 // [N]

    // ---- build CSR (by dst) ----
    initdeg_k<<<(NN + 255) / 256, 256, 0, stream>>>(deg);
    count_k<<<(EE + 255) / 256, 256, 0, stream>>>(ei, deg);
    scan_k<<<1, SCAN_T, 0, stream>>>(deg, offs, cursor);
    fill_k<<<(ETOT + 255) / 256, 256, 0, stream>>>(ei, cursor, csr);

    // ---- normalize input rows ----
    norm_k<<<NN / 4, 256, 0, stream>>>(x, A);

    dim3 ggrid((NN + 63) / 64, DD / 64);

    // layer 1: A -> B (h) -> A
    gemm_k<<<ggrid, 256, 0, stream>>>(A, W1, B);
    sd_k<<<NN / 4, 256, 0, stream>>>(B, as1, ad1, sArr, dArr);
    agg_k<<<NN / 4, 256, 0, stream>>>(B, sArr, dArr, offs, csr, b1, A);

    // layer 2: A -> B -> A
    gemm_k<<<ggrid, 256, 0, stream>>>(A, W2, B);
    sd_k<<<NN / 4, 256, 0, stream>>>(B, as2, ad2, sArr, dArr);
    agg_k<<<NN / 4, 256, 0, stream>>>(B, sArr, dArr, offs, csr, b2, A);

    // layer 3: A -> B -> d_out
    gemm_k<<<ggrid, 256, 0, stream>>>(A, W3, B);
    sd_k<<<NN / 4, 256, 0, stream>>>(B, as3, ad3, sArr, dArr);
    agg_k<<<NN / 4, 256, 0, stream>>>(B, sArr, dArr, offs, csr, b3, (float*)d_out);
}